// Round 1
// baseline (305.175 us; speedup 1.0000x reference)
//
#include <hip/hip_runtime.h>

// ---------------------------------------------------------------------------
// JobSchedulerGNN: 2-layer GraphConv (agg@W_rel + b + h@W_root, relu) + heads
// f32 everywhere this round (correctness baseline).
// Pipeline: deg-histogram -> exclusive scan -> CSR fill (reused both layers)
//           -> gather-aggregate -> fused dual-GEMM (K=256) -> heads.
// ---------------------------------------------------------------------------

#define D 128

__global__ __launch_bounds__(256) void k_count(const int* __restrict__ dst,
                                               int* __restrict__ deg, int E) {
  int e = blockIdx.x * blockDim.x + threadIdx.x;
  if (e < E) atomicAdd(&deg[dst[e]], 1);
}

// Block scans 1024 elements (256 thr x 4). Writes local-exclusive to cursor,
// block total to part.
__global__ __launch_bounds__(256) void k_scan1(const int* __restrict__ deg,
                                               int* __restrict__ cursor,
                                               int* __restrict__ part, int n) {
  __shared__ int sd[256];
  int t = threadIdx.x;
  int i0 = blockIdx.x * 1024 + t * 4;
  int v0 = (i0 + 0 < n) ? deg[i0 + 0] : 0;
  int v1 = (i0 + 1 < n) ? deg[i0 + 1] : 0;
  int v2 = (i0 + 2 < n) ? deg[i0 + 2] : 0;
  int v3 = (i0 + 3 < n) ? deg[i0 + 3] : 0;
  int s = v0 + v1 + v2 + v3;
  int incl = s;
  sd[t] = incl;
  __syncthreads();
  #pragma unroll
  for (int off = 1; off < 256; off <<= 1) {
    int add = (t >= off) ? sd[t - off] : 0;
    __syncthreads();
    incl += add;
    sd[t] = incl;
    __syncthreads();
  }
  if (t == 255) part[blockIdx.x] = incl;
  int run = incl - s;
  if (i0 + 0 < n) cursor[i0 + 0] = run; run += v0;
  if (i0 + 1 < n) cursor[i0 + 1] = run; run += v1;
  if (i0 + 2 < n) cursor[i0 + 2] = run; run += v2;
  if (i0 + 3 < n) cursor[i0 + 3] = run;
}

__global__ void k_scan2(int* part, int nblk) {
  if (threadIdx.x == 0 && blockIdx.x == 0) {
    int run = 0;
    for (int b = 0; b < nblk; b++) { int x = part[b]; part[b] = run; run += x; }
  }
}

__global__ __launch_bounds__(256) void k_scan3(int* cursor,
                                               const int* __restrict__ part,
                                               int n) {
  int add = part[blockIdx.x];
  int i0 = blockIdx.x * 1024 + threadIdx.x * 4;
  #pragma unroll
  for (int i = 0; i < 4; i++) {
    int idx = i0 + i;
    if (idx < n) cursor[idx] += add;
  }
}

// pos = bump(cursor[dst]); csr[pos] = src. After this, cursor[d] = row end.
__global__ __launch_bounds__(256) void k_fill(const int* __restrict__ ei,
                                              int* __restrict__ cursor,
                                              int* __restrict__ csr, int E) {
  int e = blockIdx.x * blockDim.x + threadIdx.x;
  if (e < E) {
    int s = ei[e];
    int d = ei[E + e];
    int pos = atomicAdd(&cursor[d], 1);
    csr[pos] = s;
  }
}

// 32 threads per node, one float4 of features each. start = cursor(end) - deg.
__global__ __launch_bounds__(256) void k_aggregate(const float* __restrict__ H,
                                                   const int* __restrict__ csr,
                                                   const int* __restrict__ cursor,
                                                   const int* __restrict__ deg,
                                                   float* __restrict__ out, int n) {
  int t = threadIdx.x;
  int node = blockIdx.x * 8 + (t >> 5);
  if (node >= n) return;
  int f = (t & 31) * 4;
  int cnt = deg[node];
  int start = cursor[node] - cnt;
  float4 s = make_float4(0.f, 0.f, 0.f, 0.f);
  for (int j = 0; j < cnt; j++) {
    int srcn = csr[start + j];
    const float4 hv = *(const float4*)&H[(size_t)srcn * D + f];
    s.x += hv.x; s.y += hv.y; s.z += hv.z; s.w += hv.w;
  }
  *(float4*)&out[(size_t)node * D + f] = s;
}

// C = relu(A1@W1 + A2@W2 + bias).  A: [n,128] f32, W: [128,128], tile 128x128.
// 256 threads, 8x8 outputs/thread as 2x2 blocks of 4x4 at (+0,+64) offsets.
__global__ __launch_bounds__(256) void k_gemm_fused(
    const float* __restrict__ A1, const float* __restrict__ W1,
    const float* __restrict__ A2, const float* __restrict__ W2,
    const float* __restrict__ bias, float* __restrict__ C, int n) {
  __shared__ float sA[16][132];  // A chunk transposed: sA[k][row]
  __shared__ float sW[16][132];  // W chunk: sW[k][col]
  const int tid = threadIdx.x;
  const int row0 = blockIdx.x * 128;
  const int tr = (tid >> 4) * 4;  // 0..60
  const int tc = (tid & 15) * 4;  // 0..60

  float acc[2][2][4][4];
  #pragma unroll
  for (int a = 0; a < 2; a++)
    #pragma unroll
    for (int b = 0; b < 2; b++)
      #pragma unroll
      for (int r = 0; r < 4; r++)
        #pragma unroll
        for (int c = 0; c < 4; c++) acc[a][b][r][c] = 0.f;

  #pragma unroll 1
  for (int pass = 0; pass < 2; ++pass) {
    const float* __restrict__ A = pass ? A2 : A1;
    const float* __restrict__ W = pass ? W2 : W1;
    #pragma unroll 1
    for (int k0 = 0; k0 < 128; k0 += 16) {
      // stage A: 128 rows x 16 k (coalesced float4, transposed into LDS)
      #pragma unroll
      for (int i = 0; i < 2; i++) {
        int slot = tid + i * 256;     // 0..511
        int r = slot >> 2;            // row 0..127
        int seg = slot & 3;           // k segment
        int grow = row0 + r;
        float4 a4 = make_float4(0.f, 0.f, 0.f, 0.f);
        if (grow < n) a4 = *(const float4*)&A[(size_t)grow * D + k0 + seg * 4];
        sA[seg * 4 + 0][r] = a4.x;
        sA[seg * 4 + 1][r] = a4.y;
        sA[seg * 4 + 2][r] = a4.z;
        sA[seg * 4 + 3][r] = a4.w;
      }
      // stage W: 16 x 128 (contiguous float4)
      #pragma unroll
      for (int i = 0; i < 2; i++) {
        int slot = tid + i * 256;
        int kr = slot >> 5;           // 0..15
        int cs = slot & 31;           // 0..31
        *(float4*)&sW[kr][cs * 4] = *(const float4*)&W[(size_t)(k0 + kr) * D + cs * 4];
      }
      __syncthreads();
      #pragma unroll
      for (int kk = 0; kk < 16; kk++) {
        float4 a0 = *(const float4*)&sA[kk][tr];
        float4 a1 = *(const float4*)&sA[kk][tr + 64];
        float4 w0 = *(const float4*)&sW[kk][tc];
        float4 w1 = *(const float4*)&sW[kk][tc + 64];
        float av[2][4] = {{a0.x, a0.y, a0.z, a0.w}, {a1.x, a1.y, a1.z, a1.w}};
        float wv[2][4] = {{w0.x, w0.y, w0.z, w0.w}, {w1.x, w1.y, w1.z, w1.w}};
        #pragma unroll
        for (int rh = 0; rh < 2; rh++)
          #pragma unroll
          for (int r = 0; r < 4; r++)
            #pragma unroll
            for (int ch = 0; ch < 2; ch++)
              #pragma unroll
              for (int c = 0; c < 4; c++)
                acc[rh][ch][r][c] += av[rh][r] * wv[ch][c];
      }
      __syncthreads();
    }
  }

  float bv[2][4];
  #pragma unroll
  for (int ch = 0; ch < 2; ch++) {
    float4 b4 = *(const float4*)&bias[ch * 64 + tc];
    bv[ch][0] = b4.x; bv[ch][1] = b4.y; bv[ch][2] = b4.z; bv[ch][3] = b4.w;
  }
  #pragma unroll
  for (int rh = 0; rh < 2; rh++)
    #pragma unroll
    for (int r = 0; r < 4; r++) {
      int grow = row0 + rh * 64 + tr + r;
      if (grow < n) {
        #pragma unroll
        for (int ch = 0; ch < 2; ch++) {
          float4 o;
          o.x = fmaxf(acc[rh][ch][r][0] + bv[ch][0], 0.f);
          o.y = fmaxf(acc[rh][ch][r][1] + bv[ch][1], 0.f);
          o.z = fmaxf(acc[rh][ch][r][2] + bv[ch][2], 0.f);
          o.w = fmaxf(acc[rh][ch][r][3] + bv[ch][3], 0.f);
          *(float4*)&C[(size_t)grow * D + ch * 64 + tc] = o;
        }
      }
    }
}

// out[0:2N] = h2@Wa + ba ; out[2N:3N] = h2@Wo + bo
__global__ __launch_bounds__(256) void k_heads(const float* __restrict__ H,
                                               const float* __restrict__ Wa,
                                               const float* __restrict__ ba,
                                               const float* __restrict__ Wo,
                                               const float* __restrict__ bo,
                                               float* __restrict__ out, int n) {
  __shared__ float sWa[256];
  __shared__ float sWo[128];
  int t = threadIdx.x;
  sWa[t] = Wa[t];
  if (t < 128) sWo[t] = Wo[t];
  __syncthreads();
  int node = blockIdx.x * 256 + t;
  if (node >= n) return;
  float a0 = 0.f, a1 = 0.f, o = 0.f;
  #pragma unroll
  for (int k4 = 0; k4 < 32; k4++) {
    float4 h = *(const float4*)&H[(size_t)node * D + k4 * 4];
    int k = k4 * 4;
    a0 += h.x * sWa[(k + 0) * 2 + 0] + h.y * sWa[(k + 1) * 2 + 0] +
          h.z * sWa[(k + 2) * 2 + 0] + h.w * sWa[(k + 3) * 2 + 0];
    a1 += h.x * sWa[(k + 0) * 2 + 1] + h.y * sWa[(k + 1) * 2 + 1] +
          h.z * sWa[(k + 2) * 2 + 1] + h.w * sWa[(k + 3) * 2 + 1];
    o  += h.x * sWo[k + 0] + h.y * sWo[k + 1] + h.z * sWo[k + 2] + h.w * sWo[k + 3];
  }
  out[(size_t)node * 2 + 0] = a0 + ba[0];
  out[(size_t)node * 2 + 1] = a1 + ba[1];
  out[(size_t)2 * n + node] = o + bo[0];
}

extern "C" void kernel_launch(void* const* d_in, const int* in_sizes, int n_in,
                              void* d_out, int out_size, void* d_ws, size_t ws_size,
                              hipStream_t stream) {
  const float* x       = (const float*)d_in[0];
  const int*   ei      = (const int*)d_in[1];
  const float* W1_rel  = (const float*)d_in[2];
  const float* b1      = (const float*)d_in[3];
  const float* W1_root = (const float*)d_in[4];
  const float* W2_rel  = (const float*)d_in[5];
  const float* b2      = (const float*)d_in[6];
  const float* W2_root = (const float*)d_in[7];
  const float* Wa      = (const float*)d_in[8];
  const float* ba      = (const float*)d_in[9];
  const float* Wo      = (const float*)d_in[10];
  const float* bo      = (const float*)d_in[11];
  float* out = (float*)d_out;

  const int N = in_sizes[0] / D;
  const int E = in_sizes[1] / 2;

  // workspace carve (all chunks 16B-aligned)
  char* w = (char*)d_ws;
  float* agg = (float*)w;  w += (size_t)N * D * sizeof(float);
  float* h1  = (float*)w;  w += (size_t)N * D * sizeof(float);
  float* h2  = (float*)w;  w += (size_t)N * D * sizeof(float);
  int* deg    = (int*)w;   w += (size_t)N * sizeof(int);
  int* cursor = (int*)w;   w += (size_t)N * sizeof(int);
  int* csr    = (int*)w;   w += (size_t)E * sizeof(int);
  int* part   = (int*)w;   w += 64 * sizeof(int);

  const int nblk = (N + 1023) / 1024;

  hipMemsetAsync(deg, 0, (size_t)N * sizeof(int), stream);
  k_count<<<(E + 255) / 256, 256, 0, stream>>>(ei + E, deg, E);
  k_scan1<<<nblk, 256, 0, stream>>>(deg, cursor, part, N);
  k_scan2<<<1, 64, 0, stream>>>(part, nblk);
  k_scan3<<<nblk, 256, 0, stream>>>(cursor, part, N);
  k_fill<<<(E + 255) / 256, 256, 0, stream>>>(ei, cursor, csr, E);

  // layer 1
  k_aggregate<<<(N + 7) / 8, 256, 0, stream>>>(x, csr, cursor, deg, agg, N);
  k_gemm_fused<<<(N + 127) / 128, 256, 0, stream>>>(agg, W1_rel, x, W1_root, b1, h1, N);
  // layer 2
  k_aggregate<<<(N + 7) / 8, 256, 0, stream>>>(h1, csr, cursor, deg, agg, N);
  k_gemm_fused<<<(N + 127) / 128, 256, 0, stream>>>(agg, W2_rel, h1, W2_root, b2, h2, N);
  // heads
  k_heads<<<(N + 255) / 256, 256, 0, stream>>>(h2, Wa, ba, Wo, bo, out, N);
}

// Round 2
// 182.927 us; speedup vs baseline: 1.6683x; 1.6683x over previous
//
#include <hip/hip_runtime.h>

// ---------------------------------------------------------------------------
// JobSchedulerGNN, round 2: bf16 everywhere that matters.
//   convert x->bf16, weights->bf16 transposed (once, tiny)
//   CSR build (reused both layers)
//   gather-aggregate in bf16 (f32 accum)
//   dual-GEMM via mfma_f32_16x16x32_bf16, register-only (no LDS, no barriers)
//   heads from bf16 h2
// ---------------------------------------------------------------------------

#define D 128

typedef unsigned short ushort8 __attribute__((ext_vector_type(8)));
typedef __bf16 bf16x8 __attribute__((ext_vector_type(8)));
typedef float f32x4 __attribute__((ext_vector_type(4)));

__device__ inline unsigned short f2bf(float f) {
  unsigned u = __float_as_uint(f);
  u += 0x7FFFu + ((u >> 16) & 1u);  // round-to-nearest-even
  return (unsigned short)(u >> 16);
}
__device__ inline float bf2f(unsigned short h) {
  return __uint_as_float((unsigned)h << 16);
}

// ---- conversions ----------------------------------------------------------

__global__ __launch_bounds__(256) void k_convert_x(const float* __restrict__ in,
                                                   unsigned short* __restrict__ out,
                                                   int total8) {
  int i = blockIdx.x * 256 + threadIdx.x;
  if (i >= total8) return;
  const float4* p = (const float4*)(in + (size_t)i * 8);
  float4 v0 = p[0], v1 = p[1];
  ushort8 o;
  o[0] = f2bf(v0.x); o[1] = f2bf(v0.y); o[2] = f2bf(v0.z); o[3] = f2bf(v0.w);
  o[4] = f2bf(v1.x); o[5] = f2bf(v1.y); o[6] = f2bf(v1.z); o[7] = f2bf(v1.w);
  *(ushort8*)(out + (size_t)i * 8) = o;
}

// 4 weight matrices [128][128] f32 -> bf16 TRANSPOSED (WT[n][k] = W[k][n]).
__global__ __launch_bounds__(256) void k_convert_w(
    const float* __restrict__ s0, const float* __restrict__ s1,
    const float* __restrict__ s2, const float* __restrict__ s3,
    unsigned short* __restrict__ d0, unsigned short* __restrict__ d1,
    unsigned short* __restrict__ d2, unsigned short* __restrict__ d3) {
  int idx = blockIdx.x * 256 + threadIdx.x;  // 0..65535
  int mat = idx >> 14;
  int rem = idx & 16383;
  int k = rem >> 7, nn = rem & 127;  // read coalesced over nn
  const float* s = (mat == 0) ? s0 : (mat == 1) ? s1 : (mat == 2) ? s2 : s3;
  unsigned short* d = (mat == 0) ? d0 : (mat == 1) ? d1 : (mat == 2) ? d2 : d3;
  d[nn * 128 + k] = f2bf(s[k * 128 + nn]);
}

// ---- CSR build ------------------------------------------------------------

__global__ __launch_bounds__(256) void k_count(const int* __restrict__ dst,
                                               int* __restrict__ deg, int E) {
  int e = blockIdx.x * blockDim.x + threadIdx.x;
  if (e < E) atomicAdd(&deg[dst[e]], 1);
}

__global__ __launch_bounds__(256) void k_scan1(const int* __restrict__ deg,
                                               int* __restrict__ cursor,
                                               int* __restrict__ part, int n) {
  __shared__ int sd[256];
  int t = threadIdx.x;
  int i0 = blockIdx.x * 1024 + t * 4;
  int v0 = (i0 + 0 < n) ? deg[i0 + 0] : 0;
  int v1 = (i0 + 1 < n) ? deg[i0 + 1] : 0;
  int v2 = (i0 + 2 < n) ? deg[i0 + 2] : 0;
  int v3 = (i0 + 3 < n) ? deg[i0 + 3] : 0;
  int s = v0 + v1 + v2 + v3;
  int incl = s;
  sd[t] = incl;
  __syncthreads();
  #pragma unroll
  for (int off = 1; off < 256; off <<= 1) {
    int add = (t >= off) ? sd[t - off] : 0;
    __syncthreads();
    incl += add;
    sd[t] = incl;
    __syncthreads();
  }
  if (t == 255) part[blockIdx.x] = incl;
  int run = incl - s;
  if (i0 + 0 < n) cursor[i0 + 0] = run; run += v0;
  if (i0 + 1 < n) cursor[i0 + 1] = run; run += v1;
  if (i0 + 2 < n) cursor[i0 + 2] = run; run += v2;
  if (i0 + 3 < n) cursor[i0 + 3] = run;
}

__global__ void k_scan2(int* part, int nblk) {
  if (threadIdx.x == 0 && blockIdx.x == 0) {
    int run = 0;
    for (int b = 0; b < nblk; b++) { int x = part[b]; part[b] = run; run += x; }
  }
}

__global__ __launch_bounds__(256) void k_scan3(int* cursor,
                                               const int* __restrict__ part,
                                               int n) {
  int add = part[blockIdx.x];
  int i0 = blockIdx.x * 1024 + threadIdx.x * 4;
  #pragma unroll
  for (int i = 0; i < 4; i++) {
    int idx = i0 + i;
    if (idx < n) cursor[idx] += add;
  }
}

__global__ __launch_bounds__(256) void k_fill(const int* __restrict__ ei,
                                              int* __restrict__ cursor,
                                              int* __restrict__ csr, int E) {
  int e = blockIdx.x * blockDim.x + threadIdx.x;
  if (e < E) {
    int s = ei[e];
    int d = ei[E + e];
    int pos = atomicAdd(&cursor[d], 1);
    csr[pos] = s;
  }
}

// ---- aggregate (bf16 rows, f32 accum) --------------------------------------
// 16 lanes per node, 8 bf16 (16B) per lane. start = cursor(end) - deg.
__global__ __launch_bounds__(256) void k_aggregate_bf(
    const unsigned short* __restrict__ H, const int* __restrict__ csr,
    const int* __restrict__ cursor, const int* __restrict__ deg,
    unsigned short* __restrict__ out, int n) {
  int t = threadIdx.x;
  int node = blockIdx.x * 16 + (t >> 4);
  if (node >= n) return;
  int f = (t & 15) * 8;
  int cnt = deg[node];
  int start = cursor[node] - cnt;
  float acc[8] = {0.f, 0.f, 0.f, 0.f, 0.f, 0.f, 0.f, 0.f};
  int j = 0;
  for (; j + 2 <= cnt; j += 2) {
    int a = csr[start + j], b = csr[start + j + 1];
    ushort8 ha = *(const ushort8*)&H[(size_t)a * D + f];
    ushort8 hb = *(const ushort8*)&H[(size_t)b * D + f];
    #pragma unroll
    for (int e = 0; e < 8; e++) acc[e] += bf2f(ha[e]) + bf2f(hb[e]);
  }
  if (j < cnt) {
    int a = csr[start + j];
    ushort8 ha = *(const ushort8*)&H[(size_t)a * D + f];
    #pragma unroll
    for (int e = 0; e < 8; e++) acc[e] += bf2f(ha[e]);
  }
  ushort8 o;
  #pragma unroll
  for (int e = 0; e < 8; e++) o[e] = f2bf(acc[e]);
  *(ushort8*)&out[(size_t)node * D + f] = o;
}

// ---- fused dual GEMM via MFMA ----------------------------------------------
// C = relu(A1@W1 + A2@W2 + bias), all [*,128]x[128,128], weights pre-transposed
// (BT[n][k]). 128-row tile, 4 waves; wave w owns rows w*32..w*32+31 (M_rep=2),
// all 128 cols (N_rep=8). Register-only: no LDS, no __syncthreads.
// A-frag: lane l reads 8 contig bf16 at A[row=(l&15)+16*mr][k0+(l>>4)*8].
// B-frag: lane l reads 8 contig bf16 at BT[col=(l&15)+16*nr][k0+(l>>4)*8].
// Same k-assignment for A and B => any HW k-permutation cancels.
// C/D layout (HW-verified): col=lane&15, row=(lane>>4)*4+reg.
__global__ __launch_bounds__(256) void k_gemm_mfma(
    const unsigned short* __restrict__ A1, const unsigned short* __restrict__ B1T,
    const unsigned short* __restrict__ A2, const unsigned short* __restrict__ B2T,
    const float* __restrict__ bias, unsigned short* __restrict__ C, int n) {
  const int tid = threadIdx.x;
  const int w = tid >> 6;
  const int l = tid & 63;
  const int lr = l & 15;
  const int kg = l >> 4;
  const int brow = blockIdx.x * 128 + w * 32;

  f32x4 acc[2][8];
  f32x4 zf = {0.f, 0.f, 0.f, 0.f};
  #pragma unroll
  for (int mr = 0; mr < 2; mr++)
    #pragma unroll
    for (int nr = 0; nr < 8; nr++) acc[mr][nr] = zf;

  #pragma unroll
  for (int pass = 0; pass < 2; pass++) {
    const unsigned short* A = pass ? A2 : A1;
    const unsigned short* BT = pass ? B2T : B1T;
    #pragma unroll
    for (int k0 = 0; k0 < 128; k0 += 32) {
      const int kb = k0 + kg * 8;
      bf16x8 a[2], b[8];
      #pragma unroll
      for (int mr = 0; mr < 2; mr++) {
        int row = brow + mr * 16 + lr;
        uint4 v = make_uint4(0u, 0u, 0u, 0u);
        if (row < n) v = *(const uint4*)&A[(size_t)row * D + kb];
        a[mr] = __builtin_bit_cast(bf16x8, v);
      }
      #pragma unroll
      for (int nr = 0; nr < 8; nr++) {
        uint4 v = *(const uint4*)&BT[(size_t)(nr * 16 + lr) * D + kb];
        b[nr] = __builtin_bit_cast(bf16x8, v);
      }
      #pragma unroll
      for (int mr = 0; mr < 2; mr++)
        #pragma unroll
        for (int nr = 0; nr < 8; nr++)
          acc[mr][nr] = __builtin_amdgcn_mfma_f32_16x16x32_bf16(a[mr], b[nr],
                                                                acc[mr][nr], 0, 0, 0);
    }
  }

  float bcol[8];
  #pragma unroll
  for (int nr = 0; nr < 8; nr++) bcol[nr] = bias[nr * 16 + lr];

  #pragma unroll
  for (int mr = 0; mr < 2; mr++)
    #pragma unroll
    for (int r = 0; r < 4; r++) {
      int row = brow + mr * 16 + kg * 4 + r;
      if (row < n) {
        #pragma unroll
        for (int nr = 0; nr < 8; nr++)
          C[(size_t)row * D + nr * 16 + lr] =
              f2bf(fmaxf(acc[mr][nr][r] + bcol[nr], 0.f));
      }
    }
}

// ---- heads ------------------------------------------------------------------
__global__ __launch_bounds__(256) void k_heads_bf(
    const unsigned short* __restrict__ H, const float* __restrict__ Wa,
    const float* __restrict__ ba, const float* __restrict__ Wo,
    const float* __restrict__ bo, float* __restrict__ out, int n) {
  __shared__ float sWa[256];
  __shared__ float sWo[128];
  int t = threadIdx.x;
  sWa[t] = Wa[t];
  if (t < 128) sWo[t] = Wo[t];
  __syncthreads();
  int node = blockIdx.x * 256 + t;
  if (node >= n) return;
  float a0 = 0.f, a1 = 0.f, o = 0.f;
  #pragma unroll
  for (int k8 = 0; k8 < 16; k8++) {
    ushort8 h = *(const ushort8*)&H[(size_t)node * D + k8 * 8];
    #pragma unroll
    for (int e = 0; e < 8; e++) {
      float hv = bf2f(h[e]);
      int k = k8 * 8 + e;
      a0 += hv * sWa[k * 2 + 0];
      a1 += hv * sWa[k * 2 + 1];
      o  += hv * sWo[k];
    }
  }
  out[(size_t)node * 2 + 0] = a0 + ba[0];
  out[(size_t)node * 2 + 1] = a1 + ba[1];
  out[(size_t)2 * n + node] = o + bo[0];
}

// ---- launch -----------------------------------------------------------------
extern "C" void kernel_launch(void* const* d_in, const int* in_sizes, int n_in,
                              void* d_out, int out_size, void* d_ws, size_t ws_size,
                              hipStream_t stream) {
  const float* x       = (const float*)d_in[0];
  const int*   ei      = (const int*)d_in[1];
  const float* W1_rel  = (const float*)d_in[2];
  const float* b1      = (const float*)d_in[3];
  const float* W1_root = (const float*)d_in[4];
  const float* W2_rel  = (const float*)d_in[5];
  const float* b2      = (const float*)d_in[6];
  const float* W2_root = (const float*)d_in[7];
  const float* Wa      = (const float*)d_in[8];
  const float* ba      = (const float*)d_in[9];
  const float* Wo      = (const float*)d_in[10];
  const float* bo      = (const float*)d_in[11];
  float* out = (float*)d_out;

  const int N = in_sizes[0] / D;
  const int E = in_sizes[1] / 2;

  char* w = (char*)d_ws;
  unsigned short* xb   = (unsigned short*)w; w += (size_t)N * D * 2;
  unsigned short* aggb = (unsigned short*)w; w += (size_t)N * D * 2;
  unsigned short* h1b  = (unsigned short*)w; w += (size_t)N * D * 2;
  unsigned short* h2b  = (unsigned short*)w; w += (size_t)N * D * 2;
  unsigned short* WT1r = (unsigned short*)w; w += 128 * 128 * 2;
  unsigned short* WT1x = (unsigned short*)w; w += 128 * 128 * 2;
  unsigned short* WT2r = (unsigned short*)w; w += 128 * 128 * 2;
  unsigned short* WT2x = (unsigned short*)w; w += 128 * 128 * 2;
  int* deg    = (int*)w; w += (size_t)N * 4;
  int* cursor = (int*)w; w += (size_t)N * 4;
  int* csr    = (int*)w; w += (size_t)E * 4;
  int* part   = (int*)w; w += 64 * 4;

  const int nblk = (N + 1023) / 1024;

  k_convert_x<<<(N * 16 + 255) / 256, 256, 0, stream>>>(x, xb, N * 16);
  k_convert_w<<<256, 256, 0, stream>>>(W1_rel, W1_root, W2_rel, W2_root,
                                       WT1r, WT1x, WT2r, WT2x);

  hipMemsetAsync(deg, 0, (size_t)N * 4, stream);
  k_count<<<(E + 255) / 256, 256, 0, stream>>>(ei + E, deg, E);
  k_scan1<<<nblk, 256, 0, stream>>>(deg, cursor, part, N);
  k_scan2<<<1, 64, 0, stream>>>(part, nblk);
  k_scan3<<<nblk, 256, 0, stream>>>(cursor, part, N);
  k_fill<<<(E + 255) / 256, 256, 0, stream>>>(ei, cursor, csr, E);

  // layer 1
  k_aggregate_bf<<<(N + 15) / 16, 256, 0, stream>>>(xb, csr, cursor, deg, aggb, N);
  k_gemm_mfma<<<(N + 127) / 128, 256, 0, stream>>>(aggb, WT1r, xb, WT1x, b1, h1b, N);
  // layer 2
  k_aggregate_bf<<<(N + 15) / 16, 256, 0, stream>>>(h1b, csr, cursor, deg, aggb, N);
  k_gemm_mfma<<<(N + 127) / 128, 256, 0, stream>>>(aggb, WT2r, h1b, WT2x, b2, h2b, N);
  // heads
  k_heads_bf<<<(N + 255) / 256, 256, 0, stream>>>(h2b, Wa, ba, Wo, bo, out, N);
}